// Round 10
// baseline (477.507 us; speedup 1.0000x reference)
//
#include <hip/hip_runtime.h>

#define HH 128
#define WW 256
#define HW (HH * WW)

// ws float offsets
#define OFF_TOT   0
#define OFF_WT    2048
#define WT_STEM   0          // [n=ci*9+k][o16]    = 1152
#define WT_1A     1152       // [tap12][ci16][o32] = 6144
#define WT_1B     7296       // [kd3][ci32][o32]   = 3072
#define WT_2A     10368      // [tap12][ci32][o64] = 24576
#define WT_2B     34944      // [kd3][ci64][o64]   = 12288
#define OFF_STEM  49280      // 24*128*256*16 = 12582912
#define OFF_F1A   12632192   // 12*64*128*32  = 3145728
#define OFF_F1N   15777920   // 3145728
#define OFF_F2A   49280      // reuse t_stem region (dead after conv1a)

// ------ kernel P: weight transposes + tot + uv ------------------------------
__global__ __launch_bounds__(256) void k_pre(
    const float* __restrict__ sp, const float* __restrict__ xy,
    const float* __restrict__ wstem, const float* __restrict__ w1a,
    const float* __restrict__ w1b, const float* __restrict__ w2a,
    const float* __restrict__ w2b,
    float* __restrict__ tot, float* __restrict__ uv_out, float* __restrict__ wt)
{
  int gid = blockIdx.x * 256 + threadIdx.x;   // 96*256 = 24576 threads
  if (gid < 1152) { int o = gid & 15, r = gid >> 4; int ci = r / 9, k = r - ci * 9;
    wt[WT_STEM + gid] = wstem[o * 72 + ci * 9 + k]; }
  if (gid < 6144) { int o = gid & 31, ci = (gid >> 5) & 15, tp = gid >> 9;
    wt[WT_1A + gid] = w1a[o * 192 + ci * 12 + tp]; }
  if (gid < 3072) { int o = gid & 31, ci = (gid >> 5) & 31, kd = gid >> 10;
    wt[WT_1B + gid] = w1b[(o * 32 + ci) * 3 + kd]; }
  if (gid < 24576) { int o = gid & 63, ci = (gid >> 6) & 31, tp = gid >> 11;
    wt[WT_2A + gid] = w2a[o * 384 + ci * 12 + tp]; }
  if (gid < 12288) { int o = gid & 63, ci = (gid >> 6) & 63, kd = gid >> 12;
    wt[WT_2B + gid] = w2b[(o * 64 + ci) * 3 + kd]; }
  if (gid < 8192) {
    int cell = gid >> 2, q = gid & 3;
    int Y = cell >> 6, X = cell & 63;
    float tsum = 0.f, u0 = 0.f, u1 = 0.f;
    int y = Y * 4 + q;
#pragma unroll
    for (int j = 0; j < 4; ++j) {
      int x = X * 4 + j;
      float psum = 0.f;
#pragma unroll
      for (int k = 0; k < 9; ++k) {
        int oy = 4 * ((k / 3) - 1), ox = 4 * ((k % 3) - 1);
        int sy = y - oy, sx = x - ox;
        if (sy >= 0 && sy < HH && sx >= 0 && sx < WW)
          psum += sp[k * HW + sy * WW + sx];
      }
      tsum += psum;
      int oy = (y >= 4) ? 4 : 0;
      int ox = (x >= 4) ? 4 : 0;
      int kk = (oy ? 2 : 1) * 3 + (ox ? 2 : 1);
      int sy = y - oy, sx = x - ox;
      float p = sp[kk * HW + sy * WW + sx];
      u0 += xy[sy * WW + sx] * p;
      u1 += xy[HW + sy * WW + sx] * p;
    }
    tsum += __shfl_xor(tsum, 1); tsum += __shfl_xor(tsum, 2);
    u0 += __shfl_xor(u0, 1); u0 += __shfl_xor(u0, 2);
    u1 += __shfl_xor(u1, 1); u1 += __shfl_xor(u1, 2);
    if (q == 0) {
      float t = tsum * (1.f / 16.f);
      tot[cell] = t;
      float inv = 1.f / t;
      uv_out[cell] = u0 * (1.f / 16.f) * inv;
      uv_out[2048 + cell] = u1 * (1.f / 16.f) * inv;
    }
  }
}

// ------------- kernel B: fused gather + normalize + stem conv ----------------
// 2px x 2 d-planes x 8o (og=2). ci-pipelined. out NDHWC [24][128][256][16]
__global__ __launch_bounds__(256) void k_stem(
    const float* __restrict__ cv, const float* __restrict__ sp,
    const float* __restrict__ wt, const float* __restrict__ tot,
    float* __restrict__ out)
{
  __shared__ float wl[576];    // [n=ci*9+k][o8-slice]
  int og = blockIdx.x & 1;
  int xh = blockIdx.x >> 1;
  for (int i = threadIdx.x; i < 576; i += 256)
    wl[i] = wt[(i >> 3) * 16 + og * 8 + (i & 7)];
  __syncthreads();
  int x0 = xh * 128 + 2 * (threadIdx.x & 63);
  int y  = blockIdx.y * 4 + (threadIdx.x >> 6);
  int d0 = blockIdx.z * 2;
  float2 p2[9]; int off[9];
#pragma unroll
  for (int k = 0; k < 9; ++k) {
    int oy = 4 * ((k / 3) - 1), ox = 4 * ((k % 3) - 1);
    int sy = y - oy, sx = x0 - ox;
    bool v = (sy >= 0) && (sy < HH) && (sx >= 0) && (sx <= WW - 2);
    int syc = v ? sy : 0, sxc = v ? sx : 0;
    off[k] = syc * WW + sxc;
    float2 t = *(const float2*)(sp + k * HW + off[k]);
    p2[k].x = v ? t.x : 0.f;
    p2[k].y = v ? t.y : 0.f;
  }
  float acc[8][2][2];          // [o][plane][px]
#pragma unroll
  for (int o = 0; o < 8; ++o)
#pragma unroll
    for (int pl = 0; pl < 2; ++pl) { acc[o][pl][0] = 0.f; acc[o][pl][1] = 0.f; }
  const float* cvd = cv + (size_t)d0 * HW;
  float2 cb[2][2][9];          // [parity][plane][k]
#pragma unroll
  for (int pl = 0; pl < 2; ++pl)
#pragma unroll
    for (int k = 0; k < 9; ++k)
      cb[0][pl][k] = *(const float2*)(cvd + (size_t)pl * HW + off[k]);
#pragma unroll
  for (int ci = 0; ci < 8; ++ci) {
    if (ci < 7) {
#pragma unroll
      for (int pl = 0; pl < 2; ++pl)
#pragma unroll
        for (int k = 0; k < 9; ++k)
          cb[(ci + 1) & 1][pl][k] =
            *(const float2*)(cvd + (size_t)(ci + 1) * 24 * HW + (size_t)pl * HW + off[k]);
    }
#pragma unroll
    for (int k = 0; k < 9; ++k) {
      float t00 = cb[ci & 1][0][k].x * p2[k].x;
      float t01 = cb[ci & 1][0][k].y * p2[k].y;
      float t10 = cb[ci & 1][1][k].x * p2[k].x;
      float t11 = cb[ci & 1][1][k].y * p2[k].y;
      const float* wb = &wl[(ci * 9 + k) * 8];
      float wv[8];
      *(float4*)&wv[0] = *(const float4*)wb;
      *(float4*)&wv[4] = *(const float4*)(wb + 4);
#pragma unroll
      for (int o = 0; o < 8; ++o) {
        acc[o][0][0] += wv[o] * t00;
        acc[o][0][1] += wv[o] * t01;
        acc[o][1][0] += wv[o] * t10;
        acc[o][1][1] += wv[o] * t11;
      }
    }
  }
  float inv = 1.f / tot[(y >> 2) * 64 + (x0 >> 2)];
#pragma unroll
  for (int pl = 0; pl < 2; ++pl) {
    float* op = out + (((size_t)(d0 + pl) * HH + y) * WW + x0) * 16 + og * 8;
#pragma unroll
    for (int px = 0; px < 2; ++px) {
      float4 v0, v1;
      v0.x = fmaxf(acc[0][pl][px] * inv, 0.f); v0.y = fmaxf(acc[1][pl][px] * inv, 0.f);
      v0.z = fmaxf(acc[2][pl][px] * inv, 0.f); v0.w = fmaxf(acc[3][pl][px] * inv, 0.f);
      v1.x = fmaxf(acc[4][pl][px] * inv, 0.f); v1.y = fmaxf(acc[5][pl][px] * inv, 0.f);
      v1.z = fmaxf(acc[6][pl][px] * inv, 0.f); v1.w = fmaxf(acc[7][pl][px] * inv, 0.f);
      *(float4*)(op + px * 16) = v0;
      *(float4*)(op + px * 16 + 4) = v1;
    }
  }
}

// ------- kernel C: conv1a (32,16,3,2,2) s(2,2,2) p(1,0,0), NO relu -----------
// ky-split partial sums: z = og*2+ky, 768 blocks. 2px x 16o per thread.
// atomicAdd pre-relu into zeroed partial buffer (relu deferred to conv1b).
__global__ __launch_bounds__(256) void k_conv1a(
    const float* __restrict__ in, const float* __restrict__ wt,
    float* __restrict__ partial)
{
  __shared__ float wl[3072];   // [tap12][ci16][o16-slice]
  int og = blockIdx.z >> 1;
  int ky = blockIdx.z & 1;
  for (int i = threadIdx.x; i < 3072; i += 256) {
    int o = i & 15, ci = (i >> 4) & 15, tap = i >> 8;
    wl[i] = wt[tap * 512 + ci * 32 + og * 16 + o];
  }
  __syncthreads();
  int xq = threadIdx.x & 63;             // out x = 2xq, 2xq+1
  int yo = blockIdx.x * 4 + (threadIdx.x >> 6);
  int dz = blockIdx.y;
  int y = 2 * yo + ky;
  float acc[16][2];
#pragma unroll
  for (int o = 0; o < 16; ++o) { acc[o][0] = 0.f; acc[o][1] = 0.f; }
  for (int kd = 0; kd < 3; ++kd) {
    int d = 2 * dz - 1 + kd;
    if (d < 0 || d >= 24) continue;      // uniform (blockIdx)
    float ib[64];                        // 4 in-px x 16 ch, contiguous 256B/lane
    const float4* ip = (const float4*)(in + (((size_t)d * 128 + y) * 256 + 4 * xq) * 16);
#pragma unroll
    for (int q = 0; q < 16; ++q) {
      float4 t = ip[q];
      ib[q * 4] = t.x; ib[q * 4 + 1] = t.y; ib[q * 4 + 2] = t.z; ib[q * 4 + 3] = t.w;
    }
#pragma unroll
    for (int kx = 0; kx < 2; ++kx) {
      const float* wtap = &wl[((kd * 2 + ky) * 2 + kx) * 256];
#pragma unroll
      for (int ci = 0; ci < 16; ++ci) {
        const float* wb = wtap + ci * 16;
        float wv[16];
#pragma unroll
        for (int q = 0; q < 4; ++q) *(float4*)&wv[q * 4] = *(const float4*)(wb + q * 4);
        float a0 = ib[(0 + kx) * 16 + ci];
        float a1 = ib[(2 + kx) * 16 + ci];
#pragma unroll
        for (int o = 0; o < 16; ++o) {
          acc[o][0] += wv[o] * a0;
          acc[o][1] += wv[o] * a1;
        }
      }
    }
  }
  float* pp = partial + (((size_t)dz * 64 + yo) * 128 + 2 * xq) * 32 + og * 16;
#pragma unroll
  for (int px = 0; px < 2; ++px)
#pragma unroll
    for (int o = 0; o < 16; ++o)
      atomicAdd(&pp[px * 32 + o], acc[o][px]);
}

// --------- kernel D: conv1b (32,32,3,1,1) p(1,0,0) + relu --------------------
// 1px x 16o. Applies deferred relu on loads of pre-relu conv1a partials.
// in [12][64][128][32] pre-relu -> outn NDHWC + outc NCDHW (d_out f1)
__global__ __launch_bounds__(256) void k_conv1b(
    const float* __restrict__ in, const float* __restrict__ wt,
    float* __restrict__ outn, float* __restrict__ outc)
{
  __shared__ float wl[3072];   // [kd][ci32][o32]
  for (int i = threadIdx.x; i < 3072; i += 256) wl[i] = wt[i];
  __syncthreads();
  int tid = threadIdx.x;
  int xo = (blockIdx.x & 1) * 64 + (tid & 63);
  int yo = (blockIdx.x >> 1) * 4 + (tid >> 6);
  int dz = blockIdx.y, og = blockIdx.z;
  float acc[16];
#pragma unroll
  for (int o = 0; o < 16; ++o) acc[o] = 0.f;
  for (int kd = 0; kd < 3; ++kd) {
    int d = dz - 1 + kd;
    if (d < 0 || d >= 12) continue;     // uniform
    float iv[32];
    const float4* ip = (const float4*)(in + (((size_t)d * 64 + yo) * 128 + xo) * 32);
#pragma unroll
    for (int q = 0; q < 8; ++q) {
      float4 v = ip[q];
      iv[q * 4 + 0] = fmaxf(v.x, 0.f); iv[q * 4 + 1] = fmaxf(v.y, 0.f);
      iv[q * 4 + 2] = fmaxf(v.z, 0.f); iv[q * 4 + 3] = fmaxf(v.w, 0.f);
    }
    const float* wk = &wl[kd * 1024 + og * 16];
#pragma unroll
    for (int ci = 0; ci < 32; ++ci) {
      const float* wb = wk + ci * 32;
      float wv[16];
#pragma unroll
      for (int q = 0; q < 4; ++q) *(float4*)&wv[q * 4] = *(const float4*)(wb + q * 4);
#pragma unroll
      for (int o = 0; o < 16; ++o) acc[o] += wv[o] * iv[ci];
    }
  }
  float* onp = outn + (((size_t)dz * 64 + yo) * 128 + xo) * 32 + og * 16;
#pragma unroll
  for (int q = 0; q < 4; ++q) {
    float4 v;
    v.x = fmaxf(acc[q * 4 + 0], 0.f);
    v.y = fmaxf(acc[q * 4 + 1], 0.f);
    v.z = fmaxf(acc[q * 4 + 2], 0.f);
    v.w = fmaxf(acc[q * 4 + 3], 0.f);
    *(float4*)(onp + q * 4) = v;
  }
#pragma unroll
  for (int o = 0; o < 16; ++o)
    outc[((size_t)((og * 16 + o) * 12 + dz) * 64 + yo) * 128 + xo] = fmaxf(acc[o], 0.f);
}

// ------- kernel E: conv2a (64,32,3,2,2) s(2,2,2) p(1,0,0) + relu -------------
// 1px x 8o (og=8). in NDHWC [12][64][128][32] -> [6][32][64][64]
__global__ __launch_bounds__(256) void k_conv2a(
    const float* __restrict__ in, const float* __restrict__ wt,
    float* __restrict__ out)
{
  __shared__ float wl[3072];   // [tap12][ci32][o8-slice]
  int og = blockIdx.z;
  for (int i = threadIdx.x; i < 3072; i += 256) {
    int o = i & 7, ci = (i >> 3) & 31, tap = i >> 8;
    wl[i] = wt[tap * 2048 + ci * 64 + og * 8 + o];
  }
  __syncthreads();
  int xo = threadIdx.x & 63;
  int yo = blockIdx.x * 4 + (threadIdx.x >> 6);
  int dz = blockIdx.y;
  float acc[8];
#pragma unroll
  for (int o = 0; o < 8; ++o) acc[o] = 0.f;
  for (int kd = 0; kd < 3; ++kd) {
    int d = 2 * dz - 1 + kd;
    if (d < 0 || d >= 12) continue;      // uniform
#pragma unroll
    for (int ky = 0; ky < 2; ++ky) {
      int y = 2 * yo + ky;
      float ib[64];                      // 2 in-px (kx) x 32 ch, contiguous
      const float4* ip = (const float4*)(in + (((size_t)d * 64 + y) * 128 + 2 * xo) * 32);
#pragma unroll
      for (int q = 0; q < 16; ++q) {
        float4 t = ip[q];
        ib[q * 4] = t.x; ib[q * 4 + 1] = t.y; ib[q * 4 + 2] = t.z; ib[q * 4 + 3] = t.w;
      }
#pragma unroll
      for (int kx = 0; kx < 2; ++kx) {
        const float* wtap = &wl[((kd * 2 + ky) * 2 + kx) * 256];
#pragma unroll
        for (int ci = 0; ci < 32; ++ci) {
          const float* wb = wtap + ci * 8;
          float wv[8];
          *(float4*)&wv[0] = *(const float4*)wb;
          *(float4*)&wv[4] = *(const float4*)(wb + 4);
          float a = ib[kx * 32 + ci];
#pragma unroll
          for (int o = 0; o < 8; ++o) acc[o] += wv[o] * a;
        }
      }
    }
  }
  float* op = out + (((size_t)dz * 32 + yo) * 64 + xo) * 64 + og * 8;
  float4 v0, v1;
  v0.x = fmaxf(acc[0], 0.f); v0.y = fmaxf(acc[1], 0.f);
  v0.z = fmaxf(acc[2], 0.f); v0.w = fmaxf(acc[3], 0.f);
  v1.x = fmaxf(acc[4], 0.f); v1.y = fmaxf(acc[5], 0.f);
  v1.z = fmaxf(acc[6], 0.f); v1.w = fmaxf(acc[7], 0.f);
  *(float4*)op = v0; *(float4*)(op + 4) = v1;
}

// --------- kernel F: conv2b (64,64,3,1,1) p(1,0,0) + relu --------------------
// 1px x 8o (og=8). in NDHWC [6][32][64][64] -> d_out f2 NCDHW (64,6,32,64)
__global__ __launch_bounds__(256) void k_conv2b(
    const float* __restrict__ in, const float* __restrict__ wt,
    float* __restrict__ out)
{
  __shared__ float wl[1536];   // [kd3][ci64][o8-slice]
  int og = blockIdx.z;
  for (int i = threadIdx.x; i < 1536; i += 256) {
    int o = i & 7, ci = (i >> 3) & 63, kd = i >> 9;
    wl[i] = wt[kd * 4096 + ci * 64 + og * 8 + o];
  }
  __syncthreads();
  int xo = threadIdx.x & 63;
  int yo = blockIdx.x * 4 + (threadIdx.x >> 6);
  int dz = blockIdx.y;
  float acc[8];
#pragma unroll
  for (int o = 0; o < 8; ++o) acc[o] = 0.f;
  for (int kd = 0; kd < 3; ++kd) {
    int d = dz - 1 + kd;
    if (d < 0 || d >= 6) continue;       // uniform
    float ib[64];
    const float4* ip = (const float4*)(in + (((size_t)d * 32 + yo) * 64 + xo) * 64);
#pragma unroll
    for (int q = 0; q < 16; ++q) {
      float4 t = ip[q];
      ib[q * 4] = t.x; ib[q * 4 + 1] = t.y; ib[q * 4 + 2] = t.z; ib[q * 4 + 3] = t.w;
    }
    const float* wk = &wl[kd * 512];
#pragma unroll
    for (int ci = 0; ci < 64; ++ci) {
      const float* wb = wk + ci * 8;
      float wv[8];
      *(float4*)&wv[0] = *(const float4*)wb;
      *(float4*)&wv[4] = *(const float4*)(wb + 4);
      float a = ib[ci];
#pragma unroll
      for (int o = 0; o < 8; ++o) acc[o] += wv[o] * a;
    }
  }
#pragma unroll
  for (int o = 0; o < 8; ++o)
    out[((size_t)((og * 8 + o) * 6 + dz) * 32 + yo) * 64 + xo] = fmaxf(acc[o], 0.f);
}

extern "C" void kernel_launch(void* const* d_in, const int* in_sizes, int n_in,
                              void* d_out, int out_size, void* d_ws, size_t ws_size,
                              hipStream_t stream) {
  const float* cv    = (const float*)d_in[0];
  const float* sp    = (const float*)d_in[1];
  const float* xy    = (const float*)d_in[2];
  const float* wstem = (const float*)d_in[3];
  const float* w1a   = (const float*)d_in[4];
  const float* w1b   = (const float*)d_in[5];
  const float* w2a   = (const float*)d_in[6];
  const float* w2b   = (const float*)d_in[7];
  float* out = (float*)d_out;
  float* out_f1 = out;
  float* out_f2 = out + 3145728;
  float* out_uv = out + 3145728 + 786432;

  float* ws = (float*)d_ws;
  float* t_tot  = ws + OFF_TOT;
  float* wt     = ws + OFF_WT;
  float* t_stem = ws + OFF_STEM;
  float* t_f1a  = ws + OFF_F1A;    // pre-relu partial sums (atomic)
  float* t_f1n  = ws + OFF_F1N;
  float* t_f2a  = ws + OFF_F2A;    // reuses t_stem region

  hipMemsetAsync(t_f1a, 0, 3145728 * sizeof(float), stream);
  k_pre<<<96, 256, 0, stream>>>(sp, xy, wstem, w1a, w1b, w2a, w2b,
                                t_tot, out_uv, wt);
  k_stem<<<dim3(4, 32, 12), 256, 0, stream>>>(cv, sp, wt + WT_STEM, t_tot, t_stem);
  k_conv1a<<<dim3(16, 12, 4), 256, 0, stream>>>(t_stem, wt + WT_1A, t_f1a);
  k_conv1b<<<dim3(32, 12, 2), 256, 0, stream>>>(t_f1a, wt + WT_1B, t_f1n, out_f1);
  k_conv2a<<<dim3(8, 6, 8), 256, 0, stream>>>(t_f1n, wt + WT_2A, t_f2a);
  k_conv2b<<<dim3(8, 6, 8), 256, 0, stream>>>(t_f2a, wt + WT_2B, out_f2);
}

// Round 11
// 171.397 us; speedup vs baseline: 2.7860x; 2.7860x over previous
//
#include <hip/hip_runtime.h>

#define HH 128
#define WW 256
#define HW (HH * WW)

// ws float offsets
#define OFF_TOT   0
#define OFF_WT    2048
#define WT_STEM   0          // [n=ci*9+k][o16]    = 1152
#define WT_1A     1152       // [tap12][ci16][o32] = 6144
#define WT_1B     7296       // [kd3][ci32][o32]   = 3072
#define WT_2A     10368      // [tap12][ci32][o64] = 24576
#define WT_2B     34944      // [kd3][ci64][o64]   = 12288
#define OFF_STEM  49280      // 24*128*256*16 = 12582912
#define OFF_F1A   12632192   // 12*64*128*32  = 3145728
#define OFF_F1N   15777920   // 3145728
#define OFF_F2A   49280      // reuse t_stem region (dead after conv1a)

// ------ kernel P: weight transposes + tot + uv ------------------------------
__global__ __launch_bounds__(256) void k_pre(
    const float* __restrict__ sp, const float* __restrict__ xy,
    const float* __restrict__ wstem, const float* __restrict__ w1a,
    const float* __restrict__ w1b, const float* __restrict__ w2a,
    const float* __restrict__ w2b,
    float* __restrict__ tot, float* __restrict__ uv_out, float* __restrict__ wt)
{
  int gid = blockIdx.x * 256 + threadIdx.x;   // 96*256 = 24576 threads
  if (gid < 1152) { int o = gid & 15, r = gid >> 4; int ci = r / 9, k = r - ci * 9;
    wt[WT_STEM + gid] = wstem[o * 72 + ci * 9 + k]; }
  if (gid < 6144) { int o = gid & 31, ci = (gid >> 5) & 15, tp = gid >> 9;
    wt[WT_1A + gid] = w1a[o * 192 + ci * 12 + tp]; }
  if (gid < 3072) { int o = gid & 31, ci = (gid >> 5) & 31, kd = gid >> 10;
    wt[WT_1B + gid] = w1b[(o * 32 + ci) * 3 + kd]; }
  if (gid < 24576) { int o = gid & 63, ci = (gid >> 6) & 31, tp = gid >> 11;
    wt[WT_2A + gid] = w2a[o * 384 + ci * 12 + tp]; }
  if (gid < 12288) { int o = gid & 63, ci = (gid >> 6) & 63, kd = gid >> 12;
    wt[WT_2B + gid] = w2b[(o * 64 + ci) * 3 + kd]; }
  if (gid < 8192) {
    int cell = gid >> 2, q = gid & 3;
    int Y = cell >> 6, X = cell & 63;
    float tsum = 0.f, u0 = 0.f, u1 = 0.f;
    int y = Y * 4 + q;
#pragma unroll
    for (int j = 0; j < 4; ++j) {
      int x = X * 4 + j;
      float psum = 0.f;
#pragma unroll
      for (int k = 0; k < 9; ++k) {
        int oy = 4 * ((k / 3) - 1), ox = 4 * ((k % 3) - 1);
        int sy = y - oy, sx = x - ox;
        if (sy >= 0 && sy < HH && sx >= 0 && sx < WW)
          psum += sp[k * HW + sy * WW + sx];
      }
      tsum += psum;
      int oy = (y >= 4) ? 4 : 0;
      int ox = (x >= 4) ? 4 : 0;
      int kk = (oy ? 2 : 1) * 3 + (ox ? 2 : 1);
      int sy = y - oy, sx = x - ox;
      float p = sp[kk * HW + sy * WW + sx];
      u0 += xy[sy * WW + sx] * p;
      u1 += xy[HW + sy * WW + sx] * p;
    }
    tsum += __shfl_xor(tsum, 1); tsum += __shfl_xor(tsum, 2);
    u0 += __shfl_xor(u0, 1); u0 += __shfl_xor(u0, 2);
    u1 += __shfl_xor(u1, 1); u1 += __shfl_xor(u1, 2);
    if (q == 0) {
      float t = tsum * (1.f / 16.f);
      tot[cell] = t;
      float inv = 1.f / t;
      uv_out[cell] = u0 * (1.f / 16.f) * inv;
      uv_out[2048 + cell] = u1 * (1.f / 16.f) * inv;
    }
  }
}

// ------------- kernel B: fused gather + normalize + stem conv ----------------
// 2 px/thread, ci-pipelined double-buffered (r6 proven). out NDHWC [24][128][256][16]
__global__ __launch_bounds__(256) void k_stem(
    const float* __restrict__ cv, const float* __restrict__ sp,
    const float* __restrict__ wt, const float* __restrict__ tot,
    float* __restrict__ out)
{
  __shared__ float wl[1152];   // [ci][k][o16]
  for (int i = threadIdx.x; i < 1152; i += 256) wl[i] = wt[i];
  __syncthreads();
  int x0 = blockIdx.x * 128 + 2 * (threadIdx.x & 63);
  int y  = blockIdx.y * 4 + (threadIdx.x >> 6);
  int d  = blockIdx.z;
  float2 p2[9]; int off[9];
#pragma unroll
  for (int k = 0; k < 9; ++k) {
    int oy = 4 * ((k / 3) - 1), ox = 4 * ((k % 3) - 1);
    int sy = y - oy, sx = x0 - ox;
    bool v = (sy >= 0) && (sy < HH) && (sx >= 0) && (sx < WW - 1);
    int syc = v ? sy : 0, sxc = v ? sx : 0;
    off[k] = syc * WW + sxc;
    float2 t = *(const float2*)(sp + k * HW + off[k]);
    p2[k].x = v ? t.x : 0.f;
    p2[k].y = v ? t.y : 0.f;
  }
  float acc[16][2];
#pragma unroll
  for (int o = 0; o < 16; ++o) { acc[o][0] = 0.f; acc[o][1] = 0.f; }
  const float* cvd = cv + (size_t)d * HW;
  float2 cb[2][9];
#pragma unroll
  for (int k = 0; k < 9; ++k) cb[0][k] = *(const float2*)(cvd + off[k]);
#pragma unroll
  for (int ci = 0; ci < 8; ++ci) {
    if (ci < 7) {
#pragma unroll
      for (int k = 0; k < 9; ++k)
        cb[(ci + 1) & 1][k] = *(const float2*)(cvd + (size_t)(ci + 1) * 24 * HW + off[k]);
    }
#pragma unroll
    for (int k = 0; k < 9; ++k) {
      float t0 = cb[ci & 1][k].x * p2[k].x;
      float t1 = cb[ci & 1][k].y * p2[k].y;
      const float* wb = &wl[(ci * 9 + k) * 16];
      float wv[16];
#pragma unroll
      for (int q = 0; q < 4; ++q) *(float4*)&wv[q * 4] = *(const float4*)(wb + q * 4);
#pragma unroll
      for (int o = 0; o < 16; ++o) {
        acc[o][0] += wv[o] * t0;
        acc[o][1] += wv[o] * t1;
      }
    }
  }
  float inv = 1.f / tot[(y >> 2) * 64 + (x0 >> 2)];
  float* op = out + (((size_t)d * HH + y) * WW + x0) * 16;
#pragma unroll
  for (int p = 0; p < 2; ++p)
#pragma unroll
    for (int q = 0; q < 4; ++q) {
      float4 v;
      v.x = fmaxf(acc[q * 4 + 0][p] * inv, 0.f);
      v.y = fmaxf(acc[q * 4 + 1][p] * inv, 0.f);
      v.z = fmaxf(acc[q * 4 + 2][p] * inv, 0.f);
      v.w = fmaxf(acc[q * 4 + 3][p] * inv, 0.f);
      *(float4*)(op + p * 16 + q * 4) = v;
    }
}

// ------- kernel C: conv1a (32,16,3,2,2) s(2,2,2) p(1,0,0) + relu -------------
// NEW: 4px x 16o (og=2), 16 FMA per weight-b128, ILP design (192 blocks).
// in NDHWC [24][128][256][16] -> out NDHWC [12][64][128][32]
__global__ __launch_bounds__(256) void k_conv1a(
    const float* __restrict__ in, const float* __restrict__ wt,
    float* __restrict__ out)
{
  __shared__ float wl[3072];   // [tap12][ci16][o16-slice]
  int og = blockIdx.z;
  for (int i = threadIdx.x; i < 3072; i += 256) {
    int o = i & 15, ci = (i >> 4) & 15, tap = i >> 8;
    wl[i] = wt[tap * 512 + ci * 32 + og * 16 + o];
  }
  __syncthreads();
  int tx = threadIdx.x & 31;           // 4 out-px each: xo = 4tx..4tx+3
  int ty = threadIdx.x >> 5;           // 8 rows/block
  int yo = blockIdx.x * 8 + ty;
  int dz = blockIdx.y;
  float acc[16][4];
#pragma unroll
  for (int o = 0; o < 16; ++o)
#pragma unroll
    for (int p = 0; p < 4; ++p) acc[o][p] = 0.f;
  for (int kd = 0; kd < 3; ++kd) {
    int d = 2 * dz - 1 + kd;
    if (d < 0 || d >= 24) continue;    // uniform
#pragma unroll
    for (int ky = 0; ky < 2; ++ky) {
      int y = 2 * yo + ky;
      const float* base = in + (((size_t)d * 128 + y) * 256 + 8 * tx) * 16;
#pragma unroll
      for (int kx = 0; kx < 2; ++kx) {
        // load 4 in-px (2p+kx for p=0..3) x 16 ch = 64 floats
        float ib[64];
#pragma unroll
        for (int p = 0; p < 4; ++p) {
          const float4* ip = (const float4*)(base + (2 * p + kx) * 16);
#pragma unroll
          for (int q = 0; q < 4; ++q) {
            float4 t = ip[q];
            ib[p * 16 + q * 4 + 0] = t.x; ib[p * 16 + q * 4 + 1] = t.y;
            ib[p * 16 + q * 4 + 2] = t.z; ib[p * 16 + q * 4 + 3] = t.w;
          }
        }
        const float* wtap = &wl[((kd * 2 + ky) * 2 + kx) * 256];
#pragma unroll
        for (int ci = 0; ci < 16; ++ci) {
          float wv[16];
#pragma unroll
          for (int q = 0; q < 4; ++q)
            *(float4*)&wv[q * 4] = *(const float4*)(wtap + ci * 16 + q * 4);
          float a0 = ib[0 * 16 + ci];
          float a1 = ib[1 * 16 + ci];
          float a2 = ib[2 * 16 + ci];
          float a3 = ib[3 * 16 + ci];
#pragma unroll
          for (int o = 0; o < 16; ++o) {
            acc[o][0] += wv[o] * a0;
            acc[o][1] += wv[o] * a1;
            acc[o][2] += wv[o] * a2;
            acc[o][3] += wv[o] * a3;
          }
        }
      }
    }
  }
  float* op = out + (((size_t)dz * 64 + yo) * 128 + 4 * tx) * 32 + og * 16;
#pragma unroll
  for (int p = 0; p < 4; ++p)
#pragma unroll
    for (int q = 0; q < 4; ++q) {
      float4 v;
      v.x = fmaxf(acc[q * 4 + 0][p], 0.f);
      v.y = fmaxf(acc[q * 4 + 1][p], 0.f);
      v.z = fmaxf(acc[q * 4 + 2][p], 0.f);
      v.w = fmaxf(acc[q * 4 + 3][p], 0.f);
      *(float4*)(op + p * 32 + q * 4) = v;
    }
}

// --------- kernel D: conv1b (32,32,3,1,1) p(1,0,0) + relu (r4 proven) --------
// 1px x 16o. in NDHWC [12][64][128][32] -> outn NDHWC + outc NCDHW (d_out f1)
__global__ __launch_bounds__(256) void k_conv1b(
    const float* __restrict__ in, const float* __restrict__ wt,
    float* __restrict__ outn, float* __restrict__ outc)
{
  __shared__ float wl[3072];   // [kd][ci32][o32]
  for (int i = threadIdx.x; i < 3072; i += 256) wl[i] = wt[i];
  __syncthreads();
  int tid = threadIdx.x;
  int xo = (blockIdx.x & 1) * 64 + (tid & 63);
  int yo = (blockIdx.x >> 1) * 4 + (tid >> 6);
  int dz = blockIdx.y, og = blockIdx.z;
  float acc[16];
#pragma unroll
  for (int o = 0; o < 16; ++o) acc[o] = 0.f;
  for (int kd = 0; kd < 3; ++kd) {
    int d = dz - 1 + kd;
    if (d < 0 || d >= 12) continue;     // uniform
    float iv[32];
    const float4* ip = (const float4*)(in + (((size_t)d * 64 + yo) * 128 + xo) * 32);
#pragma unroll
    for (int q = 0; q < 8; ++q) {
      float4 v = ip[q];
      iv[q * 4 + 0] = v.x; iv[q * 4 + 1] = v.y;
      iv[q * 4 + 2] = v.z; iv[q * 4 + 3] = v.w;
    }
    const float* wk = &wl[kd * 1024 + og * 16];
#pragma unroll
    for (int ci = 0; ci < 32; ++ci) {
      const float* wb = wk + ci * 32;
      float wv[16];
#pragma unroll
      for (int q = 0; q < 4; ++q) *(float4*)&wv[q * 4] = *(const float4*)(wb + q * 4);
#pragma unroll
      for (int o = 0; o < 16; ++o) acc[o] += wv[o] * iv[ci];
    }
  }
  float* onp = outn + (((size_t)dz * 64 + yo) * 128 + xo) * 32 + og * 16;
#pragma unroll
  for (int q = 0; q < 4; ++q) {
    float4 v;
    v.x = fmaxf(acc[q * 4 + 0], 0.f);
    v.y = fmaxf(acc[q * 4 + 1], 0.f);
    v.z = fmaxf(acc[q * 4 + 2], 0.f);
    v.w = fmaxf(acc[q * 4 + 3], 0.f);
    *(float4*)(onp + q * 4) = v;
  }
#pragma unroll
  for (int o = 0; o < 16; ++o)
    outc[((size_t)((og * 16 + o) * 12 + dz) * 64 + yo) * 128 + xo] = fmaxf(acc[o], 0.f);
}

// ------- kernel E: conv2a (64,32,3,2,2) s(2,2,2) p(1,0,0) + relu (r4) --------
// 1px x 8o (og=8). in NDHWC [12][64][128][32] -> [6][32][64][64]
__global__ __launch_bounds__(256) void k_conv2a(
    const float* __restrict__ in, const float* __restrict__ wt,
    float* __restrict__ out)
{
  __shared__ float wl[3072];   // [tap12][ci32][o8-slice]
  int og = blockIdx.z;
  for (int i = threadIdx.x; i < 3072; i += 256) {
    int o = i & 7, ci = (i >> 3) & 31, tap = i >> 8;
    wl[i] = wt[tap * 2048 + ci * 64 + og * 8 + o];
  }
  __syncthreads();
  int xo = threadIdx.x & 63;
  int yo = blockIdx.x * 4 + (threadIdx.x >> 6);
  int dz = blockIdx.y;
  float acc[8];
#pragma unroll
  for (int o = 0; o < 8; ++o) acc[o] = 0.f;
  for (int kd = 0; kd < 3; ++kd) {
    int d = 2 * dz - 1 + kd;
    if (d < 0 || d >= 12) continue;      // uniform
#pragma unroll
    for (int ky = 0; ky < 2; ++ky) {
      int y = 2 * yo + ky;
      float ib[64];                      // 2 in-px (kx) x 32 ch, contiguous
      const float4* ip = (const float4*)(in + (((size_t)d * 64 + y) * 128 + 2 * xo) * 32);
#pragma unroll
      for (int q = 0; q < 16; ++q) {
        float4 t = ip[q];
        ib[q * 4] = t.x; ib[q * 4 + 1] = t.y; ib[q * 4 + 2] = t.z; ib[q * 4 + 3] = t.w;
      }
#pragma unroll
      for (int kx = 0; kx < 2; ++kx) {
        const float* wtap = &wl[((kd * 2 + ky) * 2 + kx) * 256];
#pragma unroll
        for (int ci = 0; ci < 32; ++ci) {
          const float* wb = wtap + ci * 8;
          float wv[8];
          *(float4*)&wv[0] = *(const float4*)wb;
          *(float4*)&wv[4] = *(const float4*)(wb + 4);
          float a = ib[kx * 32 + ci];
#pragma unroll
          for (int o = 0; o < 8; ++o) acc[o] += wv[o] * a;
        }
      }
    }
  }
  float* op = out + (((size_t)dz * 32 + yo) * 64 + xo) * 64 + og * 8;
  float4 v0, v1;
  v0.x = fmaxf(acc[0], 0.f); v0.y = fmaxf(acc[1], 0.f);
  v0.z = fmaxf(acc[2], 0.f); v0.w = fmaxf(acc[3], 0.f);
  v1.x = fmaxf(acc[4], 0.f); v1.y = fmaxf(acc[5], 0.f);
  v1.z = fmaxf(acc[6], 0.f); v1.w = fmaxf(acc[7], 0.f);
  *(float4*)op = v0; *(float4*)(op + 4) = v1;
}

// --------- kernel F: conv2b (64,64,3,1,1) p(1,0,0) + relu (r4) ---------------
// 1px x 8o (og=8). in NDHWC [6][32][64][64] -> d_out f2 NCDHW (64,6,32,64)
__global__ __launch_bounds__(256) void k_conv2b(
    const float* __restrict__ in, const float* __restrict__ wt,
    float* __restrict__ out)
{
  __shared__ float wl[1536];   // [kd3][ci64][o8-slice]
  int og = blockIdx.z;
  for (int i = threadIdx.x; i < 1536; i += 256) {
    int o = i & 7, ci = (i >> 3) & 63, kd = i >> 9;
    wl[i] = wt[kd * 4096 + ci * 64 + og * 8 + o];
  }
  __syncthreads();
  int xo = threadIdx.x & 63;
  int yo = blockIdx.x * 4 + (threadIdx.x >> 6);
  int dz = blockIdx.y;
  float acc[8];
#pragma unroll
  for (int o = 0; o < 8; ++o) acc[o] = 0.f;
  for (int kd = 0; kd < 3; ++kd) {
    int d = dz - 1 + kd;
    if (d < 0 || d >= 6) continue;       // uniform
    float ib[64];
    const float4* ip = (const float4*)(in + (((size_t)d * 32 + yo) * 64 + xo) * 64);
#pragma unroll
    for (int q = 0; q < 16; ++q) {
      float4 t = ip[q];
      ib[q * 4] = t.x; ib[q * 4 + 1] = t.y; ib[q * 4 + 2] = t.z; ib[q * 4 + 3] = t.w;
    }
    const float* wk = &wl[kd * 512];
#pragma unroll
    for (int ci = 0; ci < 64; ++ci) {
      const float* wb = wk + ci * 8;
      float wv[8];
      *(float4*)&wv[0] = *(const float4*)wb;
      *(float4*)&wv[4] = *(const float4*)(wb + 4);
      float a = ib[ci];
#pragma unroll
      for (int o = 0; o < 8; ++o) acc[o] += wv[o] * a;
    }
  }
#pragma unroll
  for (int o = 0; o < 8; ++o)
    out[((size_t)((og * 8 + o) * 6 + dz) * 32 + yo) * 64 + xo] = fmaxf(acc[o], 0.f);
}

extern "C" void kernel_launch(void* const* d_in, const int* in_sizes, int n_in,
                              void* d_out, int out_size, void* d_ws, size_t ws_size,
                              hipStream_t stream) {
  const float* cv    = (const float*)d_in[0];
  const float* sp    = (const float*)d_in[1];
  const float* xy    = (const float*)d_in[2];
  const float* wstem = (const float*)d_in[3];
  const float* w1a   = (const float*)d_in[4];
  const float* w1b   = (const float*)d_in[5];
  const float* w2a   = (const float*)d_in[6];
  const float* w2b   = (const float*)d_in[7];
  float* out = (float*)d_out;
  float* out_f1 = out;
  float* out_f2 = out + 3145728;
  float* out_uv = out + 3145728 + 786432;

  float* ws = (float*)d_ws;
  float* t_tot  = ws + OFF_TOT;
  float* wt     = ws + OFF_WT;
  float* t_stem = ws + OFF_STEM;
  float* t_f1a  = ws + OFF_F1A;
  float* t_f1n  = ws + OFF_F1N;
  float* t_f2a  = ws + OFF_F2A;    // reuses t_stem region

  k_pre<<<96, 256, 0, stream>>>(sp, xy, wstem, w1a, w1b, w2a, w2b,
                                t_tot, out_uv, wt);
  k_stem<<<dim3(2, 32, 24), 256, 0, stream>>>(cv, sp, wt + WT_STEM, t_tot, t_stem);
  k_conv1a<<<dim3(8, 12, 2), 256, 0, stream>>>(t_stem, wt + WT_1A, t_f1a);
  k_conv1b<<<dim3(32, 12, 2), 256, 0, stream>>>(t_f1a, wt + WT_1B, t_f1n, out_f1);
  k_conv2a<<<dim3(8, 6, 8), 256, 0, stream>>>(t_f1n, wt + WT_2A, t_f2a);
  k_conv2b<<<dim3(8, 6, 8), 256, 0, stream>>>(t_f2a, wt + WT_2B, out_f2);
}